// Round 5
// baseline (2057.959 us; speedup 1.0000x reference)
//
#include <hip/hip_runtime.h>

typedef _Float16 half8 __attribute__((ext_vector_type(8)));
typedef float floatx4 __attribute__((ext_vector_type(4)));

// ---------------- LayerNorm: fp32 in -> fp16 out, one wave per row of 512 ----
__global__ __launch_bounds__(64) void ln_k(const float* __restrict__ x,
                                           const float* __restrict__ gamma,
                                           const float* __restrict__ beta,
                                           _Float16* __restrict__ xn) {
    const int D = 512;
    long long base = (long long)blockIdx.x * D;
    int lane = threadIdx.x;
    floatx4 x0 = *(const floatx4*)(x + base + lane * 8);
    floatx4 x1 = *(const floatx4*)(x + base + lane * 8 + 4);
    float f[8];
#pragma unroll
    for (int i = 0; i < 4; i++) { f[i] = x0[i]; f[4 + i] = x1[i]; }
    float s = 0.f, ss = 0.f;
#pragma unroll
    for (int i = 0; i < 8; i++) { s += f[i]; ss += f[i] * f[i]; }
#pragma unroll
    for (int off = 32; off; off >>= 1) { s += __shfl_xor(s, off); ss += __shfl_xor(ss, off); }
    float mean = s * (1.f / 512.f);
    float var = ss * (1.f / 512.f) - mean * mean;
    float rstd = rsqrtf(var + 1e-6f);
    floatx4 g0 = *(const floatx4*)(gamma + lane * 8);
    floatx4 g1 = *(const floatx4*)(gamma + lane * 8 + 4);
    floatx4 b0 = *(const floatx4*)(beta + lane * 8);
    floatx4 b1 = *(const floatx4*)(beta + lane * 8 + 4);
    half8 o;
#pragma unroll
    for (int i = 0; i < 4; i++) {
        o[i]     = (_Float16)((f[i]     - mean) * rstd * g0[i] + b0[i]);
        o[4 + i] = (_Float16)((f[4 + i] - mean) * rstd * g1[i] + b1[i]);
    }
    *(half8*)(xn + base + lane * 8) = o;
}

// ------------- Transpose + convert: fp32 [Z,R,C] -> fp16 [Z,C,R] -------------
__global__ __launch_bounds__(256) void tr_k(const float* __restrict__ in,
                                            _Float16* __restrict__ out, int R, int C) {
    __shared__ _Float16 tile[32][33];
    int tx = threadIdx.x, ty = threadIdx.y;
    long long zo = (long long)blockIdx.z * R * C;
    int r0 = blockIdx.y * 32, c0 = blockIdx.x * 32;
    for (int yy = ty; yy < 32; yy += 8)
        tile[yy][tx] = (_Float16)in[zo + (long long)(r0 + yy) * C + c0 + tx];
    __syncthreads();
    for (int yy = ty; yy < 32; yy += 8)
        out[zo + (long long)(c0 + yy) * R + r0 + tx] = tile[tx][yy];
}

// ---------------- GEMM: C[M,N] = A[M,K] * Bt[N,K]^T, fp16 MFMA ---------------
// cflags: bit0 out dtype (0=f16,1=f32), bit2 causal tile skip, bit3 causal kend
// per-z: A += z*sA, Bt += z*sB, C += z*sC (elements)
#define BM 128
#define BN 128
#define BK 32
#define LPAD 8
__global__ __launch_bounds__(256) void gemm_bt(
    const _Float16* __restrict__ A, const _Float16* __restrict__ Bt, void* __restrict__ Cv,
    int K, int ldc, int cflags, long long sA, long long sB, long long sC) {
    int z = blockIdx.z;
    const _Float16* Ab = A + (long long)z * sA;
    const _Float16* Bb = Bt + (long long)z * sB;
    long long offC = (long long)z * sC;

    int m0 = blockIdx.y * BM;
    int n0 = blockIdx.x * BN;
    if ((cflags & 4) && n0 > m0 + (BM - 1)) return;  // fully-masked causal tile
    int kend = (cflags & 8) ? min(K, m0 + BM) : K;

    __shared__ _Float16 As[BM][BK + LPAD];
    __shared__ _Float16 Bs[BN][BK + LPAD];

    int t = threadIdx.x;
    int row = t >> 2;             // 0..63
    int colc = (t & 3) * 8;       // 0,8,16,24
    int lane = t & 63;
    int w = t >> 6;
    int wm = (w >> 1) * 64;
    int wn = (w & 1) * 64;
    int lm = lane & 15;
    int lk = (lane >> 4) * 8;

    floatx4 acc[4][4];
#pragma unroll
    for (int i = 0; i < 4; i++)
#pragma unroll
        for (int j = 0; j < 4; j++) acc[i][j] = floatx4{0.f, 0.f, 0.f, 0.f};

    for (int k0 = 0; k0 < kend; k0 += BK) {
        half8 av0 = *(const half8*)(Ab + (long long)(m0 + row) * K + k0 + colc);
        half8 av1 = *(const half8*)(Ab + (long long)(m0 + 64 + row) * K + k0 + colc);
        half8 bv0 = *(const half8*)(Bb + (long long)(n0 + row) * K + k0 + colc);
        half8 bv1 = *(const half8*)(Bb + (long long)(n0 + 64 + row) * K + k0 + colc);
        __syncthreads();
        *(half8*)&As[row][colc] = av0;
        *(half8*)&As[64 + row][colc] = av1;
        *(half8*)&Bs[row][colc] = bv0;
        *(half8*)&Bs[64 + row][colc] = bv1;
        __syncthreads();
        half8 af[4], bfr[4];
#pragma unroll
        for (int i = 0; i < 4; i++) af[i] = *(const half8*)&As[wm + i * 16 + lm][lk];
#pragma unroll
        for (int j = 0; j < 4; j++) bfr[j] = *(const half8*)&Bs[wn + j * 16 + lm][lk];
#pragma unroll
        for (int i = 0; i < 4; i++)
#pragma unroll
            for (int j = 0; j < 4; j++)
                acc[i][j] = __builtin_amdgcn_mfma_f32_16x16x32_f16(af[i], bfr[j], acc[i][j], 0, 0, 0);
    }

    int cr = (lane >> 4) * 4;  // C/D layout: col=lane&15, row=(lane>>4)*4+reg (m89-verified)
    int cc = lm;
    bool outf32 = (cflags & 1) != 0;
#pragma unroll
    for (int i = 0; i < 4; i++) {
#pragma unroll
        for (int j = 0; j < 4; j++) {
            int rr = m0 + wm + i * 16 + cr;
            int nn = n0 + wn + j * 16 + cc;
#pragma unroll
            for (int r2 = 0; r2 < 4; r2++) {
                long long idx = (long long)(rr + r2) * ldc + nn + offC;
                float val = acc[i][j][r2];
                if (outf32) ((float*)Cv)[idx] = val;
                else ((_Float16*)Cv)[idx] = (_Float16)val;
            }
        }
    }
}

// ------- Causal softmax, in-place on fp16 scores [S,S], one wave per row -----
__global__ __launch_bounds__(256) void softmax_h(_Float16* __restrict__ sc, int S) {
    int wid = threadIdx.x >> 6, lane = threadIdx.x & 63;
    int row = blockIdx.x * 4 + wid;
    _Float16* srow = sc + (long long)row * S;
    half8 hv[4];
    float v[32];
    float mx = -3.0e38f;
#pragma unroll
    for (int c = 0; c < 4; c++) {
        hv[c] = *(half8*)(srow + lane * 8 + c * 512);
#pragma unroll
        for (int i = 0; i < 8; i++) {
            int n = lane * 8 + c * 512 + i;
            float s = (n <= row) ? (float)hv[c][i] : -3.0e38f;
            v[c * 8 + i] = s; mx = fmaxf(mx, s);
        }
    }
#pragma unroll
    for (int off = 32; off; off >>= 1) mx = fmaxf(mx, __shfl_xor(mx, off));
    float sum = 0.f;
#pragma unroll
    for (int c = 0; c < 4; c++)
#pragma unroll
        for (int i = 0; i < 8; i++) {
            int n = lane * 8 + c * 512 + i;
            float e = (n <= row) ? __expf(v[c * 8 + i] - mx) : 0.f;
            v[c * 8 + i] = e; sum += e;
        }
#pragma unroll
    for (int off = 32; off; off >>= 1) sum += __shfl_xor(sum, off);
    float inv = 1.f / sum;
#pragma unroll
    for (int c = 0; c < 4; c++) {
        half8 o;
#pragma unroll
        for (int i = 0; i < 8; i++) o[i] = (_Float16)(v[c * 8 + i] * inv);
        *(half8*)(srow + lane * 8 + c * 512) = o;
    }
}

extern "C" void kernel_launch(void* const* d_in, const int* in_sizes, int n_in,
                              void* d_out, int out_size, void* d_ws, size_t ws_size,
                              hipStream_t stream) {
    const int B = 4, S = 2048, D = 512, H = 4, U = 1024;
    const float* x     = (const float*)d_in[0];
    const float* gamma = (const float*)d_in[1];
    const float* beta  = (const float*)d_in[2];
    const float* Wq    = (const float*)d_in[3];
    const float* Wk    = (const float*)d_in[4];
    const float* Wv    = (const float*)d_in[5];
    const float* Wout  = (const float*)d_in[6];
    float* out = (float*)d_out;

    // Workspace: 96 MiB (R2 demonstrated accesses to 112 MiB don't fault).
    char* ws = (char*)d_ws;
    const size_t MiB = 1ull << 20;
    _Float16* xn   = (_Float16*)(ws + 0);         //  8 MiB [B*S, D]
    _Float16* WqT  = (_Float16*)(ws + 8  * MiB);  //  4 MiB [H, U, D]
    _Float16* WkT  = (_Float16*)(ws + 12 * MiB);  //  4 MiB
    _Float16* WvT  = (_Float16*)(ws + 16 * MiB);  //  4 MiB
    _Float16* WoT  = (_Float16*)(ws + 20 * MiB);  //  4 MiB [D, H*U]
    _Float16* qb   = (_Float16*)(ws + 24 * MiB);  // 16 MiB [H,S,U] (per batch)
    _Float16* kb   = (_Float16*)(ws + 40 * MiB);  // 16 MiB
    _Float16* vTb  = (_Float16*)(ws + 56 * MiB);  // 16 MiB [H,U,S]
    _Float16* catb = (_Float16*)(ws + 72 * MiB);  // 16 MiB [S,H*U]
    _Float16* sc   = (_Float16*)(ws + 88 * MiB);  //  8 MiB [S,S] fp16, in-place softmax

    const long long SD = (long long)S * D, UD = (long long)U * D;
    const long long SU = (long long)S * U, US = (long long)U * S;

    tr_k<<<dim3(U / 32, D / 32, H), dim3(32, 8), 0, stream>>>(Wq, WqT, D, U);
    tr_k<<<dim3(U / 32, D / 32, H), dim3(32, 8), 0, stream>>>(Wk, WkT, D, U);
    tr_k<<<dim3(U / 32, D / 32, H), dim3(32, 8), 0, stream>>>(Wv, WvT, D, U);
    tr_k<<<dim3(D / 32, (H * U) / 32, 1), dim3(32, 8), 0, stream>>>(Wout, WoT, H * U, D);
    ln_k<<<B * S, 64, 0, stream>>>(x, gamma, beta, xn);

    for (int b = 0; b < B; b++) {
        const _Float16* xnb = xn + (long long)b * SD;
        // q[h] = xn_b @ WqT[h]^T  (M=S, N=U, K=D), z=h
        gemm_bt<<<dim3(U / 128, S / 128, H), 256, 0, stream>>>(xnb, WqT, qb, D, U, 0,
            0, UD, SU);
        gemm_bt<<<dim3(U / 128, S / 128, H), 256, 0, stream>>>(xnb, WkT, kb, D, U, 0,
            0, UD, SU);
        // vT[h] = WvT[h] @ xn_b^T (M=U, N=S, K=D) -> v stored transposed
        gemm_bt<<<dim3(S / 128, U / 128, H), 256, 0, stream>>>(WvT, xnb, vTb, D, S, 0,
            UD, 0, US);
        for (int h = 0; h < H; h++) {
            // scores = q_h @ k_h^T, fp16 out, skip fully-masked tiles
            gemm_bt<<<dim3(S / 128, S / 128, 1), 256, 0, stream>>>(qb + (long long)h * SU,
                kb + (long long)h * SU, sc, U, S, 4, 0, 0, 0);
            softmax_h<<<S / 4, 256, 0, stream>>>(sc, S);
            // cat_b[:, h*U:(h+1)*U] = probs @ vT_h^T (M=S, N=U, K=S, kend=m0+128)
            gemm_bt<<<dim3(U / 128, S / 128, 1), 256, 0, stream>>>(sc,
                vTb + (long long)h * US, (void*)(catb + (long long)h * U), S, H * U, 8,
                0, 0, 0);
        }
        // out_b = cat_b @ WoT^T (M=S, N=D, K=H*U), fp32 out at element offset b*S*D
        gemm_bt<<<dim3(D / 128, S / 128, 1), 256, 0, stream>>>(catb, WoT,
            (void*)(out + (long long)b * SD), H * U, D, 1, 0, 0, 0);
    }
}

// Round 6
// 939.071 us; speedup vs baseline: 2.1915x; 2.1915x over previous
//
#include <hip/hip_runtime.h>

typedef _Float16 half8 __attribute__((ext_vector_type(8)));
typedef float floatx4 __attribute__((ext_vector_type(4)));

// async global->LDS, 16B per lane (dest = wave-uniform base + lane*16)
__device__ __forceinline__ void gl16(const _Float16* g, _Float16* l) {
    __builtin_amdgcn_global_load_lds((const __attribute__((address_space(1))) void*)g,
                                     (__attribute__((address_space(3))) void*)l, 16, 0, 0);
}

// ---------------- LayerNorm: fp32 in -> fp16 out, one wave per row of 512 ----
__global__ __launch_bounds__(64) void ln_k(const float* __restrict__ x,
                                           const float* __restrict__ gamma,
                                           const float* __restrict__ beta,
                                           _Float16* __restrict__ xn) {
    const int D = 512;
    long long base = (long long)blockIdx.x * D;
    int lane = threadIdx.x;
    floatx4 x0 = *(const floatx4*)(x + base + lane * 8);
    floatx4 x1 = *(const floatx4*)(x + base + lane * 8 + 4);
    float f[8];
#pragma unroll
    for (int i = 0; i < 4; i++) { f[i] = x0[i]; f[4 + i] = x1[i]; }
    float s = 0.f, ss = 0.f;
#pragma unroll
    for (int i = 0; i < 8; i++) { s += f[i]; ss += f[i] * f[i]; }
#pragma unroll
    for (int off = 32; off; off >>= 1) { s += __shfl_xor(s, off); ss += __shfl_xor(ss, off); }
    float mean = s * (1.f / 512.f);
    float var = ss * (1.f / 512.f) - mean * mean;
    float rstd = rsqrtf(var + 1e-6f);
    floatx4 g0 = *(const floatx4*)(gamma + lane * 8);
    floatx4 g1 = *(const floatx4*)(gamma + lane * 8 + 4);
    floatx4 b0 = *(const floatx4*)(beta + lane * 8);
    floatx4 b1 = *(const floatx4*)(beta + lane * 8 + 4);
    half8 o;
#pragma unroll
    for (int i = 0; i < 4; i++) {
        o[i]     = (_Float16)((f[i]     - mean) * rstd * g0[i] + b0[i]);
        o[4 + i] = (_Float16)((f[4 + i] - mean) * rstd * g1[i] + b1[i]);
    }
    *(half8*)(xn + base + lane * 8) = o;
}

// ------------- Transpose + convert: fp32 [Z,R,C] -> fp16 [Z,C,R] -------------
__global__ __launch_bounds__(256) void tr_k(const float* __restrict__ in,
                                            _Float16* __restrict__ out, int R, int C) {
    __shared__ _Float16 tile[32][33];
    int tx = threadIdx.x, ty = threadIdx.y;
    long long zo = (long long)blockIdx.z * R * C;
    int r0 = blockIdx.y * 32, c0 = blockIdx.x * 32;
    for (int yy = ty; yy < 32; yy += 8)
        tile[yy][tx] = (_Float16)in[zo + (long long)(r0 + yy) * C + c0 + tx];
    __syncthreads();
    for (int yy = ty; yy < 32; yy += 8)
        out[zo + (long long)(c0 + yy) * R + r0 + tx] = tile[tx][yy];
}

// ---------------- GEMM: C[M,N] = A[M,K] * Bt[N,K]^T, fp16 MFMA ---------------
// global_load_lds(16B) staging, unpadded LDS [128][32] (m97 structure).
// cflags: bit0 out f32 (else f16), bit2 causal tile skip, bit3 causal kend
// per-z: offA=((z/dA)%mA)*sA, offB=((z/dB)%mB)*sB, offC=z*sC (elements)
#define BM 128
#define BN 128
#define BK 32
__global__ __launch_bounds__(256) void gemm_bt(
    const _Float16* __restrict__ A, const _Float16* __restrict__ Bt, void* __restrict__ Cv,
    int K, int ldc, int cflags,
    int dA, int mA, long long sA, int dB, int mB, long long sB, long long sC) {
    int z = blockIdx.z;
    const _Float16* Ab = A + (long long)((z / dA) % mA) * sA;
    const _Float16* Bb = Bt + (long long)((z / dB) % mB) * sB;
    long long offC = (long long)z * sC;

    int m0 = blockIdx.y * BM, n0 = blockIdx.x * BN;
    if ((cflags & 4) && n0 > m0 + (BM - 1)) return;  // fully-masked causal tile
    int kend = (cflags & 8) ? min(K, m0 + BM) : K;

    __shared__ _Float16 As[BM * BK];
    __shared__ _Float16 Bs[BN * BK];

    int t = threadIdx.x;
    int srow = t >> 2;            // staging row 0..63
    int scol = (t & 3) * 8;       // staging col (halfs)
    int lane = t & 63, w = t >> 6;
    int wm = (w >> 1) * 64, wn = (w & 1) * 64;
    int lm = lane & 15, lk = (lane >> 4) * 8;

    floatx4 acc[4][4];
#pragma unroll
    for (int i = 0; i < 4; i++)
#pragma unroll
        for (int j = 0; j < 4; j++) acc[i][j] = floatx4{0.f, 0.f, 0.f, 0.f};

    const _Float16* ga0 = Ab + (long long)(m0 + srow) * K + scol;
    const _Float16* ga1 = Ab + (long long)(m0 + 64 + srow) * K + scol;
    const _Float16* gb0 = Bb + (long long)(n0 + srow) * K + scol;
    const _Float16* gb1 = Bb + (long long)(n0 + 64 + srow) * K + scol;
    _Float16* la0 = As + t * 8;  _Float16* la1 = As + 2048 + t * 8;
    _Float16* lb0 = Bs + t * 8;  _Float16* lb1 = Bs + 2048 + t * 8;

    for (int k0 = 0; k0 < kend; k0 += BK) {
        __syncthreads();                 // prior reads done before overwrite
        gl16(ga0 + k0, la0);
        gl16(ga1 + k0, la1);
        gl16(gb0 + k0, lb0);
        gl16(gb1 + k0, lb1);
        __syncthreads();                 // staging visible (vmcnt drained)
        half8 af[4], bfr[4];
#pragma unroll
        for (int i = 0; i < 4; i++) af[i] = *(const half8*)&As[(wm + i * 16 + lm) * BK + lk];
#pragma unroll
        for (int j = 0; j < 4; j++) bfr[j] = *(const half8*)&Bs[(wn + j * 16 + lm) * BK + lk];
#pragma unroll
        for (int i = 0; i < 4; i++)
#pragma unroll
            for (int j = 0; j < 4; j++)
                acc[i][j] = __builtin_amdgcn_mfma_f32_16x16x32_f16(af[i], bfr[j], acc[i][j], 0, 0, 0);
    }

    int cr = (lane >> 4) * 4;  // C/D: col=lane&15, row=(lane>>4)*4+reg (m89-verified)
    int cc = lm;
    bool outf32 = (cflags & 1) != 0;
#pragma unroll
    for (int i = 0; i < 4; i++) {
#pragma unroll
        for (int j = 0; j < 4; j++) {
            int rr = m0 + wm + i * 16 + cr;
            int nn = n0 + wn + j * 16 + cc;
#pragma unroll
            for (int r2 = 0; r2 < 4; r2++) {
                long long idx = (long long)(rr + r2) * ldc + nn + offC;
                float val = acc[i][j][r2];
                if (outf32) ((float*)Cv)[idx] = val;
                else ((_Float16*)Cv)[idx] = (_Float16)val;
            }
        }
    }
}

// ------- Causal softmax, in-place fp16, rows batched over (head,seq) ---------
// Only touches 512-col chunks 0..(r>>9); coverage >= m0+128 for PV's kend. 
__global__ __launch_bounds__(256) void softmax_h(_Float16* __restrict__ sc, int S) {
    int wid = threadIdx.x >> 6, lane = threadIdx.x & 63;
    int idx = blockIdx.x * 4 + wid;
    int r = idx & (S - 1);
    _Float16* srow = sc + (long long)idx * S;
    int nc = r >> 9;  // last 512-col chunk with any unmasked element
    float v[32];
    float mx = -3.0e38f;
    for (int c = 0; c <= nc; c++) {
        half8 hv = *(half8*)(srow + lane * 8 + c * 512);
#pragma unroll
        for (int i = 0; i < 8; i++) {
            int n = lane * 8 + c * 512 + i;
            float s = (n <= r) ? (float)hv[i] : -3.0e38f;
            v[c * 8 + i] = s; mx = fmaxf(mx, s);
        }
    }
#pragma unroll
    for (int off = 32; off; off >>= 1) mx = fmaxf(mx, __shfl_xor(mx, off));
    float sum = 0.f;
    for (int c = 0; c <= nc; c++)
#pragma unroll
        for (int i = 0; i < 8; i++) {
            int n = lane * 8 + c * 512 + i;
            float e = (n <= r) ? __expf(v[c * 8 + i] - mx) : 0.f;
            v[c * 8 + i] = e; sum += e;
        }
#pragma unroll
    for (int off = 32; off; off >>= 1) sum += __shfl_xor(sum, off);
    float inv = 1.f / sum;
    for (int c = 0; c <= nc; c++) {
        half8 o;
#pragma unroll
        for (int i = 0; i < 8; i++) o[i] = (_Float16)(v[c * 8 + i] * inv);
        *(half8*)(srow + lane * 8 + c * 512) = o;
    }
}

extern "C" void kernel_launch(void* const* d_in, const int* in_sizes, int n_in,
                              void* d_out, int out_size, void* d_ws, size_t ws_size,
                              hipStream_t stream) {
    const int B = 4, S = 2048, D = 512, H = 4, U = 1024;
    const float* x     = (const float*)d_in[0];
    const float* gamma = (const float*)d_in[1];
    const float* beta  = (const float*)d_in[2];
    const float* Wq    = (const float*)d_in[3];
    const float* Wk    = (const float*)d_in[4];
    const float* Wv    = (const float*)d_in[5];
    const float* Wout  = (const float*)d_in[6];
    float* out = (float*)d_out;

    char* ws = (char*)d_ws;
    const size_t MiB = 1ull << 20;
    const long long SD = (long long)S * D, UD = (long long)U * D;
    const long long SU = (long long)S * U, SS = (long long)S * S, US = (long long)U * S;
    const long long HU = (long long)H * U;

    // Common prefix (both paths): weights^T + LN.  W regions MUST stay adjacent
    // (WqT..WkT fused-z projection spans both).
    _Float16* xn  = (_Float16*)(ws + 0);         //  8 MiB [B*S, D]
    _Float16* WqT = (_Float16*)(ws + 8  * MiB);  //  4 MiB [H, U, D]
    _Float16* WkT = (_Float16*)(ws + 12 * MiB);  //  4 MiB (adjacent to WqT!)
    _Float16* WvT = (_Float16*)(ws + 16 * MiB);  //  4 MiB
    _Float16* WoT = (_Float16*)(ws + 20 * MiB);  //  4 MiB [D, H*U]

    tr_k<<<dim3(U / 32, D / 32, H), dim3(32, 8), 0, stream>>>(Wq, WqT, D, U);
    tr_k<<<dim3(U / 32, D / 32, H), dim3(32, 8), 0, stream>>>(Wk, WkT, D, U);
    tr_k<<<dim3(U / 32, D / 32, H), dim3(32, 8), 0, stream>>>(Wv, WvT, D, U);
    tr_k<<<dim3(D / 32, (H * U) / 32, 1), dim3(32, 8), 0, stream>>>(Wout, WoT, H * U, D);
    ln_k<<<B * S, 64, 0, stream>>>(x, gamma, beta, xn);

    if (ws_size >= 168 * MiB) {
        // ---- fast path: 168 MiB, fully z-batched, single out-GEMM ----
        _Float16* qb  = (_Float16*)(ws + 24  * MiB);  // 16 MiB [H,S,U] (per batch)
        _Float16* kb  = (_Float16*)(ws + 40  * MiB);  // 16 MiB (adjacent to qb!)
        _Float16* vTb = (_Float16*)(ws + 56  * MiB);  // 16 MiB [H,U,S]
        _Float16* sc  = (_Float16*)(ws + 72  * MiB);  // 32 MiB [H,S,S]
        _Float16* cat = (_Float16*)(ws + 104 * MiB);  // 64 MiB [B*S, H*U]

        for (int b = 0; b < B; b++) {
            const _Float16* xnb = xn + (long long)b * SD;
            // fused q&k proj: z in [0,8): B-ptr walks WqT then WkT, C walks qb then kb
            gemm_bt<<<dim3(U / 128, S / 128, 2 * H), 256, 0, stream>>>(xnb, WqT, qb, D, U, 0,
                1, 1, 0, 1, 2 * H, UD, SU);
            // vT[h] = WvT[h] @ xn_b^T
            gemm_bt<<<dim3(S / 128, U / 128, H), 256, 0, stream>>>(WvT, xnb, vTb, D, S, 0,
                1, H, UD, 1, 1, 0, US);
            // scores[h] = q_h @ k_h^T (f16, causal skip)
            gemm_bt<<<dim3(S / 128, S / 128, H), 256, 0, stream>>>(qb, kb, sc, U, S, 4,
                1, H, SU, 1, H, SU, SS);
            softmax_h<<<H * S / 4, 256, 0, stream>>>(sc, S);
            // cat_b[:, h*U:(h+1)*U] = P_h @ vT_h^T (kend = m0+128)
            gemm_bt<<<dim3(U / 128, S / 128, H), 256, 0, stream>>>(sc, vTb,
                (void*)(cat + (long long)b * S * HU), S, H * U, 8,
                1, H, SS, 1, H, US, U);
        }
        // out = cat @ WoT^T  (M=B*S=8192, N=D, K=H*U), fp32
        gemm_bt<<<dim3(D / 128, (B * S) / 128, 1), 256, 0, stream>>>(cat, WoT, out,
            H * U, D, 1, 1, 1, 0, 1, 1, 0, 0);
    } else {
        // ---- fallback: 96 MiB (proven safe in R5), per-head attention ----
        _Float16* qb   = (_Float16*)(ws + 24 * MiB);  // 16 MiB [H,S,U]
        _Float16* kb   = (_Float16*)(ws + 40 * MiB);  // 16 MiB (adjacent)
        _Float16* vTb  = (_Float16*)(ws + 56 * MiB);  // 16 MiB [H,U,S]
        _Float16* catb = (_Float16*)(ws + 72 * MiB);  // 16 MiB [S,H*U]
        _Float16* sc   = (_Float16*)(ws + 88 * MiB);  //  8 MiB [S,S]

        for (int b = 0; b < B; b++) {
            const _Float16* xnb = xn + (long long)b * SD;
            gemm_bt<<<dim3(U / 128, S / 128, 2 * H), 256, 0, stream>>>(xnb, WqT, qb, D, U, 0,
                1, 1, 0, 1, 2 * H, UD, SU);
            gemm_bt<<<dim3(S / 128, U / 128, H), 256, 0, stream>>>(WvT, xnb, vTb, D, S, 0,
                1, H, UD, 1, 1, 0, US);
            for (int h = 0; h < H; h++) {
                gemm_bt<<<dim3(S / 128, S / 128, 1), 256, 0, stream>>>(qb + (long long)h * SU,
                    kb + (long long)h * SU, sc, U, S, 4, 1, 1, 0, 1, 1, 0, 0);
                softmax_h<<<S / 4, 256, 0, stream>>>(sc, S);
                gemm_bt<<<dim3(U / 128, S / 128, 1), 256, 0, stream>>>(sc,
                    vTb + (long long)h * US, (void*)(catb + (long long)h * U), S, H * U, 8,
                    1, 1, 0, 1, 1, 0, 0);
            }
            gemm_bt<<<dim3(D / 128, S / 128, 1), 256, 0, stream>>>(catb, WoT,
                (void*)(out + (long long)b * SD), H * U, D, 1, 1, 1, 0, 1, 1, 0, 0);
        }
    }
}

// Round 7
// 744.252 us; speedup vs baseline: 2.7651x; 1.2618x over previous
//
#include <hip/hip_runtime.h>

typedef _Float16 half8 __attribute__((ext_vector_type(8)));
typedef float floatx4 __attribute__((ext_vector_type(4)));

// async global->LDS, 16B per lane (dest = wave-uniform base + lane*16)
__device__ __forceinline__ void gl16(const _Float16* g, _Float16* l) {
    __builtin_amdgcn_global_load_lds((const __attribute__((address_space(1))) void*)g,
                                     (__attribute__((address_space(3))) void*)l, 16, 0, 0);
}

// ---------------- LayerNorm: fp32 in -> fp16 out, one wave per row of 512 ----
__global__ __launch_bounds__(64) void ln_k(const float* __restrict__ x,
                                           const float* __restrict__ gamma,
                                           const float* __restrict__ beta,
                                           _Float16* __restrict__ xn) {
    const int D = 512;
    long long base = (long long)blockIdx.x * D;
    int lane = threadIdx.x;
    floatx4 x0 = *(const floatx4*)(x + base + lane * 8);
    floatx4 x1 = *(const floatx4*)(x + base + lane * 8 + 4);
    float f[8];
#pragma unroll
    for (int i = 0; i < 4; i++) { f[i] = x0[i]; f[4 + i] = x1[i]; }
    float s = 0.f, ss = 0.f;
#pragma unroll
    for (int i = 0; i < 8; i++) { s += f[i]; ss += f[i] * f[i]; }
#pragma unroll
    for (int off = 32; off; off >>= 1) { s += __shfl_xor(s, off); ss += __shfl_xor(ss, off); }
    float mean = s * (1.f / 512.f);
    float var = ss * (1.f / 512.f) - mean * mean;
    float rstd = rsqrtf(var + 1e-6f);
    floatx4 g0 = *(const floatx4*)(gamma + lane * 8);
    floatx4 g1 = *(const floatx4*)(gamma + lane * 8 + 4);
    floatx4 b0 = *(const floatx4*)(beta + lane * 8);
    floatx4 b1 = *(const floatx4*)(beta + lane * 8 + 4);
    half8 o;
#pragma unroll
    for (int i = 0; i < 4; i++) {
        o[i]     = (_Float16)((f[i]     - mean) * rstd * g0[i] + b0[i]);
        o[4 + i] = (_Float16)((f[4 + i] - mean) * rstd * g1[i] + b1[i]);
    }
    *(half8*)(xn + base + lane * 8) = o;
}

// ------------- Transpose + convert: fp32 [Z,R,C] -> fp16 [Z,C,R] -------------
__global__ __launch_bounds__(256) void tr_k(const float* __restrict__ in,
                                            _Float16* __restrict__ out, int R, int C) {
    __shared__ _Float16 tile[32][33];
    int tx = threadIdx.x, ty = threadIdx.y;
    long long zo = (long long)blockIdx.z * R * C;
    int r0 = blockIdx.y * 32, c0 = blockIdx.x * 32;
    for (int yy = ty; yy < 32; yy += 8)
        tile[yy][tx] = (_Float16)in[zo + (long long)(r0 + yy) * C + c0 + tx];
    __syncthreads();
    for (int yy = ty; yy < 32; yy += 8)
        out[zo + (long long)(c0 + yy) * R + r0 + tx] = tile[tx][yy];
}

// ---------------- GEMM: C[M,N] = A[M,K] * Bt[N,K]^T, fp16 MFMA ---------------
// Double-buffered global_load_lds(16B) staging (1 barrier per K-step) +
// XCD-contiguous supertile swizzle for L2 locality.
// cflags: bit0 out f32 (else f16), bit2 causal tile skip, bit3 causal kend
// per-z: offA=((z/dA)%mA)*sA, offB=((z/dB)%mB)*sB, offC=z*sC (elements)
#define BM 128
#define BN 128
#define BK 32
__global__ __launch_bounds__(256) void gemm_bt(
    const _Float16* __restrict__ A, const _Float16* __restrict__ Bt, void* __restrict__ Cv,
    int K, int ldc, int cflags,
    int dA, int mA, long long sA, int dB, int mB, long long sB, long long sC) {
    int z = blockIdx.z;
    const _Float16* Ab = A + (long long)((z / dA) % mA) * sA;
    const _Float16* Bb = Bt + (long long)((z / dB) % mB) * sB;
    long long offC = (long long)z * sC;

    // ---- block swizzle: XCD-contiguous chunks of a 4-wide-panel virtual order
    int gx = gridDim.x, gy = gridDim.y;
    int nb = gx * gy;
    int lin = blockIdx.y * gx + blockIdx.x;
    int mIdx, nIdx;
    if (((nb & 7) == 0) && ((gx & 3) == 0)) {
        int chunk = nb >> 3;
        int vid = (lin >> 3) + chunk * (lin & 7);   // same XCD -> contiguous vids
        int panelH = gy * 4;
        int panel = vid / panelH;
        int rem = vid - panel * panelH;
        mIdx = rem >> 2;
        nIdx = (panel << 2) + (rem & 3);
    } else { mIdx = blockIdx.y; nIdx = blockIdx.x; }
    int m0 = mIdx * BM, n0 = nIdx * BN;

    if ((cflags & 4) && n0 > m0 + (BM - 1)) return;  // fully-masked causal tile
    int kend = (cflags & 8) ? min(K, m0 + BM) : K;

    __shared__ _Float16 As[2][BM * BK];
    __shared__ _Float16 Bs[2][BN * BK];

    int t = threadIdx.x;
    int srow = t >> 2;            // staging row 0..63
    int scol = (t & 3) * 8;       // staging col (halfs)
    int lane = t & 63, w = t >> 6;
    int wm = (w >> 1) * 64, wn = (w & 1) * 64;
    int lm = lane & 15, lk = (lane >> 4) * 8;

    floatx4 acc[4][4];
#pragma unroll
    for (int i = 0; i < 4; i++)
#pragma unroll
        for (int j = 0; j < 4; j++) acc[i][j] = floatx4{0.f, 0.f, 0.f, 0.f};

    const _Float16* ga0 = Ab + (long long)(m0 + srow) * K + scol;
    const _Float16* ga1 = Ab + (long long)(m0 + 64 + srow) * K + scol;
    const _Float16* gb0 = Bb + (long long)(n0 + srow) * K + scol;
    const _Float16* gb1 = Bb + (long long)(n0 + 64 + srow) * K + scol;

    int nIter = kend / BK;
    // prologue: stage buffer 0
    gl16(ga0, &As[0][t * 8]);
    gl16(ga1, &As[0][2048 + t * 8]);
    gl16(gb0, &Bs[0][t * 8]);
    gl16(gb1, &Bs[0][2048 + t * 8]);

    for (int it = 0; it < nIter; it++) {
        __syncthreads();              // drains staging of cur (vmcnt) + fences prev reads
        int cur = it & 1;
        half8 af[4], bfr[4];
#pragma unroll
        for (int i = 0; i < 4; i++) af[i] = *(const half8*)&As[cur][(wm + i * 16 + lm) * BK + lk];
#pragma unroll
        for (int j = 0; j < 4; j++) bfr[j] = *(const half8*)&Bs[cur][(wn + j * 16 + lm) * BK + lk];
        if (it + 1 < nIter) {
            int nk = (it + 1) * BK;
            int nxt = cur ^ 1;
            gl16(ga0 + nk, &As[nxt][t * 8]);
            gl16(ga1 + nk, &As[nxt][2048 + t * 8]);
            gl16(gb0 + nk, &Bs[nxt][t * 8]);
            gl16(gb1 + nk, &Bs[nxt][2048 + t * 8]);
        }
#pragma unroll
        for (int i = 0; i < 4; i++)
#pragma unroll
            for (int j = 0; j < 4; j++)
                acc[i][j] = __builtin_amdgcn_mfma_f32_16x16x32_f16(af[i], bfr[j], acc[i][j], 0, 0, 0);
    }

    int cr = (lane >> 4) * 4;  // C/D: col=lane&15, row=(lane>>4)*4+reg (m89-verified)
    int cc = lm;
    bool outf32 = (cflags & 1) != 0;
#pragma unroll
    for (int i = 0; i < 4; i++) {
#pragma unroll
        for (int j = 0; j < 4; j++) {
            int rr = m0 + wm + i * 16 + cr;
            int nn = n0 + wn + j * 16 + cc;
#pragma unroll
            for (int r2 = 0; r2 < 4; r2++) {
                long long idx = (long long)(rr + r2) * ldc + nn + offC;
                float val = acc[i][j][r2];
                if (outf32) ((float*)Cv)[idx] = val;
                else ((_Float16*)Cv)[idx] = (_Float16)val;
            }
        }
    }
}

// ------- Causal softmax, in-place fp16, rows batched over (head,seq) ---------
__global__ __launch_bounds__(256) void softmax_h(_Float16* __restrict__ sc, int S) {
    int wid = threadIdx.x >> 6, lane = threadIdx.x & 63;
    int idx = blockIdx.x * 4 + wid;
    int r = idx & (S - 1);
    _Float16* srow = sc + (long long)idx * S;
    int nc = r >> 9;  // last 512-col chunk with any unmasked element
    float v[32];
    float mx = -3.0e38f;
    for (int c = 0; c <= nc; c++) {
        half8 hv = *(half8*)(srow + lane * 8 + c * 512);
#pragma unroll
        for (int i = 0; i < 8; i++) {
            int n = lane * 8 + c * 512 + i;
            float s = (n <= r) ? (float)hv[i] : -3.0e38f;
            v[c * 8 + i] = s; mx = fmaxf(mx, s);
        }
    }
#pragma unroll
    for (int off = 32; off; off >>= 1) mx = fmaxf(mx, __shfl_xor(mx, off));
    float sum = 0.f;
    for (int c = 0; c <= nc; c++)
#pragma unroll
        for (int i = 0; i < 8; i++) {
            int n = lane * 8 + c * 512 + i;
            float e = (n <= r) ? __expf(v[c * 8 + i] - mx) : 0.f;
            v[c * 8 + i] = e; sum += e;
        }
#pragma unroll
    for (int off = 32; off; off >>= 1) sum += __shfl_xor(sum, off);
    float inv = 1.f / sum;
    for (int c = 0; c <= nc; c++) {
        half8 o;
#pragma unroll
        for (int i = 0; i < 8; i++) o[i] = (_Float16)(v[c * 8 + i] * inv);
        *(half8*)(srow + lane * 8 + c * 512) = o;
    }
}

extern "C" void kernel_launch(void* const* d_in, const int* in_sizes, int n_in,
                              void* d_out, int out_size, void* d_ws, size_t ws_size,
                              hipStream_t stream) {
    const int B = 4, S = 2048, D = 512, H = 4, U = 1024;
    const float* x     = (const float*)d_in[0];
    const float* gamma = (const float*)d_in[1];
    const float* beta  = (const float*)d_in[2];
    const float* Wq    = (const float*)d_in[3];
    const float* Wk    = (const float*)d_in[4];
    const float* Wv    = (const float*)d_in[5];
    const float* Wout  = (const float*)d_in[6];
    float* out = (float*)d_out;

    char* ws = (char*)d_ws;
    const size_t MiB = 1ull << 20;
    const long long SD = (long long)S * D, UD = (long long)U * D;
    const long long SU = (long long)S * U, SS = (long long)S * S, US = (long long)U * S;
    const long long HU = (long long)H * U;

    // W regions must stay adjacent (fused-z q&k projection spans WqT..WkT).
    _Float16* xn  = (_Float16*)(ws + 0);         //  8 MiB [B*S, D]
    _Float16* WqT = (_Float16*)(ws + 8  * MiB);  //  4 MiB [H, U, D]
    _Float16* WkT = (_Float16*)(ws + 12 * MiB);  //  4 MiB (adjacent to WqT!)
    _Float16* WvT = (_Float16*)(ws + 16 * MiB);  //  4 MiB
    _Float16* WoT = (_Float16*)(ws + 20 * MiB);  //  4 MiB [D, H*U]

    tr_k<<<dim3(U / 32, D / 32, H), dim3(32, 8), 0, stream>>>(Wq, WqT, D, U);
    tr_k<<<dim3(U / 32, D / 32, H), dim3(32, 8), 0, stream>>>(Wk, WkT, D, U);
    tr_k<<<dim3(U / 32, D / 32, H), dim3(32, 8), 0, stream>>>(Wv, WvT, D, U);
    tr_k<<<dim3(D / 32, (H * U) / 32, 1), dim3(32, 8), 0, stream>>>(Wout, WoT, H * U, D);
    ln_k<<<B * S, 64, 0, stream>>>(x, gamma, beta, xn);

    if (ws_size >= 168 * MiB) {
        // ---- fast path: 168 MiB (validated in R6) ----
        _Float16* qb  = (_Float16*)(ws + 24  * MiB);  // 16 MiB [H,S,U] (per batch)
        _Float16* kb  = (_Float16*)(ws + 40  * MiB);  // 16 MiB (adjacent to qb!)
        _Float16* vTb = (_Float16*)(ws + 56  * MiB);  // 16 MiB [H,U,S]
        _Float16* sc  = (_Float16*)(ws + 72  * MiB);  // 32 MiB [H,S,S]
        _Float16* cat = (_Float16*)(ws + 104 * MiB);  // 64 MiB [B*S, H*U]

        for (int b = 0; b < B; b++) {
            const _Float16* xnb = xn + (long long)b * SD;
            // fused q&k proj: z in [0,8): B walks WqT then WkT, C walks qb then kb
            gemm_bt<<<dim3(U / 128, S / 128, 2 * H), 256, 0, stream>>>(xnb, WqT, qb, D, U, 0,
                1, 1, 0, 1, 2 * H, UD, SU);
            gemm_bt<<<dim3(S / 128, U / 128, H), 256, 0, stream>>>(WvT, xnb, vTb, D, S, 0,
                1, H, UD, 1, 1, 0, US);
            gemm_bt<<<dim3(S / 128, S / 128, H), 256, 0, stream>>>(qb, kb, sc, U, S, 4,
                1, H, SU, 1, H, SU, SS);
            softmax_h<<<H * S / 4, 256, 0, stream>>>(sc, S);
            gemm_bt<<<dim3(U / 128, S / 128, H), 256, 0, stream>>>(sc, vTb,
                (void*)(cat + (long long)b * S * HU), S, H * U, 8,
                1, H, SS, 1, H, US, U);
        }
        gemm_bt<<<dim3(D / 128, (B * S) / 128, 1), 256, 0, stream>>>(cat, WoT, out,
            H * U, D, 1, 1, 1, 0, 1, 1, 0, 0);
    } else {
        // ---- fallback: 96 MiB ----
        _Float16* qb   = (_Float16*)(ws + 24 * MiB);
        _Float16* kb   = (_Float16*)(ws + 40 * MiB);
        _Float16* vTb  = (_Float16*)(ws + 56 * MiB);
        _Float16* catb = (_Float16*)(ws + 72 * MiB);
        _Float16* sc   = (_Float16*)(ws + 88 * MiB);

        for (int b = 0; b < B; b++) {
            const _Float16* xnb = xn + (long long)b * SD;
            gemm_bt<<<dim3(U / 128, S / 128, 2 * H), 256, 0, stream>>>(xnb, WqT, qb, D, U, 0,
                1, 1, 0, 1, 2 * H, UD, SU);
            gemm_bt<<<dim3(S / 128, U / 128, H), 256, 0, stream>>>(WvT, xnb, vTb, D, S, 0,
                1, H, UD, 1, 1, 0, US);
            for (int h = 0; h < H; h++) {
                gemm_bt<<<dim3(S / 128, S / 128, 1), 256, 0, stream>>>(qb + (long long)h * SU,
                    kb + (long long)h * SU, sc, U, S, 4, 1, 1, 0, 1, 1, 0, 0);
                softmax_h<<<S / 4, 256, 0, stream>>>(sc, S);
                gemm_bt<<<dim3(U / 128, S / 128, 1), 256, 0, stream>>>(sc,
                    vTb + (long long)h * US, (void*)(catb + (long long)h * U), S, H * U, 8,
                    1, 1, 0, 1, 1, 0, 0);
            }
            gemm_bt<<<dim3(D / 128, S / 128, 1), 256, 0, stream>>>(catb, WoT,
                (void*)(out + (long long)b * SD), H * U, D, 1, 1, 1, 0, 1, 1, 0, 0);
        }
    }
}

// Round 8
// 742.598 us; speedup vs baseline: 2.7713x; 1.0022x over previous
//
#include <hip/hip_runtime.h>

typedef _Float16 half8 __attribute__((ext_vector_type(8)));
typedef float floatx4 __attribute__((ext_vector_type(4)));

// async global->LDS, 16B per lane (dest = wave-uniform base + lane*16)
__device__ __forceinline__ void gl16(const _Float16* g, _Float16* l) {
    __builtin_amdgcn_global_load_lds((const __attribute__((address_space(1))) void*)g,
                                     (__attribute__((address_space(3))) void*)l, 16, 0, 0);
}

// problem constants
#define Scst 2048
#define Dcst 512
#define Ucst 1024
#define Hcst 4
#define SDo 1048576LL   // S*D
#define UDo 524288LL    // U*D
#define SUo 2097152LL   // S*U
#define SSo 4194304LL   // S*S
#define USo 2097152LL   // U*S
#define SHUo 8388608LL  // S*H*U

// ---------------- LayerNorm: fp32 in -> fp16 out, one wave per row of 512 ----
__global__ __launch_bounds__(64) void ln_k(const float* __restrict__ x,
                                           const float* __restrict__ gamma,
                                           const float* __restrict__ beta,
                                           _Float16* __restrict__ xn) {
    const int D = 512;
    long long base = (long long)blockIdx.x * D;
    int lane = threadIdx.x;
    floatx4 x0 = *(const floatx4*)(x + base + lane * 8);
    floatx4 x1 = *(const floatx4*)(x + base + lane * 8 + 4);
    float f[8];
#pragma unroll
    for (int i = 0; i < 4; i++) { f[i] = x0[i]; f[4 + i] = x1[i]; }
    float s = 0.f, ss = 0.f;
#pragma unroll
    for (int i = 0; i < 8; i++) { s += f[i]; ss += f[i] * f[i]; }
#pragma unroll
    for (int off = 32; off; off >>= 1) { s += __shfl_xor(s, off); ss += __shfl_xor(ss, off); }
    float mean = s * (1.f / 512.f);
    float var = ss * (1.f / 512.f) - mean * mean;
    float rstd = rsqrtf(var + 1e-6f);
    floatx4 g0 = *(const floatx4*)(gamma + lane * 8);
    floatx4 g1 = *(const floatx4*)(gamma + lane * 8 + 4);
    floatx4 b0 = *(const floatx4*)(beta + lane * 8);
    floatx4 b1 = *(const floatx4*)(beta + lane * 8 + 4);
    half8 o;
#pragma unroll
    for (int i = 0; i < 4; i++) {
        o[i]     = (_Float16)((f[i]     - mean) * rstd * g0[i] + b0[i]);
        o[4 + i] = (_Float16)((f[4 + i] - mean) * rstd * g1[i] + b1[i]);
    }
    *(half8*)(xn + base + lane * 8) = o;
}

// ------------- Transpose + convert: fp32 [Z,R,C] -> fp16 [Z,C,R] -------------
__global__ __launch_bounds__(256) void tr_k(const float* __restrict__ in,
                                            _Float16* __restrict__ out, int R, int C) {
    __shared__ _Float16 tile[32][33];
    int tx = threadIdx.x, ty = threadIdx.y;
    long long zo = (long long)blockIdx.z * R * C;
    int r0 = blockIdx.y * 32, c0 = blockIdx.x * 32;
    for (int yy = ty; yy < 32; yy += 8)
        tile[yy][tx] = (_Float16)in[zo + (long long)(r0 + yy) * C + c0 + tx];
    __syncthreads();
    for (int yy = ty; yy < 32; yy += 8)
        out[zo + (long long)(c0 + yy) * R + r0 + tx] = tile[tx][yy];
}

// ---------------- GEMM: C[M,N] = A[M,K] * Bt[N,K]^T, fp16 MFMA ---------------
// Double-buffered global_load_lds(16B) staging + XCD supertile swizzle.
// cflags: bit0 out f32 (else f16), bit2 causal tile skip, bit3 causal kend
// mode: per-z offset schema (pair-batched fast path / fallback)
#define BM 128
#define BN 128
#define BK 32
__global__ __launch_bounds__(256) void gemm_bt(
    const _Float16* __restrict__ A, const _Float16* __restrict__ Bt, void* __restrict__ Cv,
    int K, int ldc, int cflags, int mode) {
    int z = blockIdx.z;
    long long offA = 0, offB = 0, offC = 0;
    switch (mode) {
        case 1:  // fast projQK: z = qk*8 + b2*4 + h
            offA = (long long)((z >> 2) & 1) * SDo;
            offB = (long long)(((z >> 3) * 4) + (z & 3)) * UDo;
            offC = (long long)(((z >> 3) * 8) + ((z & 3) * 2) + ((z >> 2) & 1)) * SUo;
            break;
        case 2:  // fast scores: z = h*2 + b2
            offA = (long long)z * SUo; offB = (long long)z * SUo; offC = (long long)z * SSo;
            break;
        case 3:  // fast projV: z = h*2 + b2
            offA = (long long)(z >> 1) * UDo; offB = (long long)(z & 1) * SDo;
            offC = (long long)z * USo;
            break;
        case 4:  // fast PV: z = h*2 + b2
            offA = (long long)z * SSo; offB = (long long)z * USo;
            offC = (long long)(z & 1) * SHUo + (long long)(z >> 1) * Ucst;
            break;
        case 6:  // fallback projQK: z = qk*4 + h
            offB = (long long)(z & 7) * UDo; offC = (long long)z * SUo;
            break;
        case 7:  // fallback projV: z = h
            offA = (long long)(z & 3) * UDo; offC = (long long)z * USo;
            break;
        default: break;  // 0: generic, offsets 0
    }
    const _Float16* Ab = A + offA;
    const _Float16* Bb = Bt + offB;

    // ---- block swizzle: XCD-contiguous chunks of a 4-wide-panel virtual order
    int gx = gridDim.x, gy = gridDim.y;
    int nb = gx * gy;
    int lin = blockIdx.y * gx + blockIdx.x;
    int mIdx, nIdx;
    if (((nb & 7) == 0) && ((gx & 3) == 0)) {
        int chunk = nb >> 3;
        int vid = (lin >> 3) + chunk * (lin & 7);
        int panelH = gy * 4;
        int panel = vid / panelH;
        int rem = vid - panel * panelH;
        mIdx = rem >> 2;
        nIdx = (panel << 2) + (rem & 3);
    } else { mIdx = blockIdx.y; nIdx = blockIdx.x; }
    int m0 = mIdx * BM, n0 = nIdx * BN;

    if ((cflags & 4) && n0 > m0 + (BM - 1)) return;  // fully-masked causal tile
    int kend = (cflags & 8) ? min(K, m0 + BM) : K;

    __shared__ _Float16 As[2][BM * BK];
    __shared__ _Float16 Bs[2][BN * BK];

    int t = threadIdx.x;
    int srow = t >> 2;            // staging row 0..63
    int scol = (t & 3) * 8;       // staging col (halfs)
    int lane = t & 63, w = t >> 6;
    int wm = (w >> 1) * 64, wn = (w & 1) * 64;
    int lm = lane & 15, lk = (lane >> 4) * 8;

    floatx4 acc[4][4];
#pragma unroll
    for (int i = 0; i < 4; i++)
#pragma unroll
        for (int j = 0; j < 4; j++) acc[i][j] = floatx4{0.f, 0.f, 0.f, 0.f};

    const _Float16* ga0 = Ab + (long long)(m0 + srow) * K + scol;
    const _Float16* ga1 = Ab + (long long)(m0 + 64 + srow) * K + scol;
    const _Float16* gb0 = Bb + (long long)(n0 + srow) * K + scol;
    const _Float16* gb1 = Bb + (long long)(n0 + 64 + srow) * K + scol;

    int nIter = kend / BK;
    gl16(ga0, &As[0][t * 8]);
    gl16(ga1, &As[0][2048 + t * 8]);
    gl16(gb0, &Bs[0][t * 8]);
    gl16(gb1, &Bs[0][2048 + t * 8]);

    for (int it = 0; it < nIter; it++) {
        __syncthreads();              // drains cur staging (vmcnt) + fences prev reads
        int cur = it & 1;
        half8 af[4], bfr[4];
#pragma unroll
        for (int i = 0; i < 4; i++) af[i] = *(const half8*)&As[cur][(wm + i * 16 + lm) * BK + lk];
#pragma unroll
        for (int j = 0; j < 4; j++) bfr[j] = *(const half8*)&Bs[cur][(wn + j * 16 + lm) * BK + lk];
        if (it + 1 < nIter) {
            int nk = (it + 1) * BK;
            int nxt = cur ^ 1;
            gl16(ga0 + nk, &As[nxt][t * 8]);
            gl16(ga1 + nk, &As[nxt][2048 + t * 8]);
            gl16(gb0 + nk, &Bs[nxt][t * 8]);
            gl16(gb1 + nk, &Bs[nxt][2048 + t * 8]);
        }
#pragma unroll
        for (int i = 0; i < 4; i++)
#pragma unroll
            for (int j = 0; j < 4; j++)
                acc[i][j] = __builtin_amdgcn_mfma_f32_16x16x32_f16(af[i], bfr[j], acc[i][j], 0, 0, 0);
    }

    int cr = (lane >> 4) * 4;  // C/D: col=lane&15, row=(lane>>4)*4+reg (m89-verified)
    int cc = lm;
    bool outf32 = (cflags & 1) != 0;
#pragma unroll
    for (int i = 0; i < 4; i++) {
#pragma unroll
        for (int j = 0; j < 4; j++) {
            int rr = m0 + wm + i * 16 + cr;
            int nn = n0 + wn + j * 16 + cc;
#pragma unroll
            for (int r2 = 0; r2 < 4; r2++) {
                long long idx = (long long)(rr + r2) * ldc + nn + offC;
                float val = acc[i][j][r2];
                if (outf32) ((float*)Cv)[idx] = val;
                else ((_Float16*)Cv)[idx] = (_Float16)val;
            }
        }
    }
}

// ------- Causal softmax, in-place fp16, rows batched over (z',seq) -----------
__global__ __launch_bounds__(256) void softmax_h(_Float16* __restrict__ sc, int S) {
    int wid = threadIdx.x >> 6, lane = threadIdx.x & 63;
    int idx = blockIdx.x * 4 + wid;
    int r = idx & (S - 1);
    _Float16* srow = sc + (long long)idx * S;
    int nc = r >> 9;  // last 512-col chunk with any unmasked element
    float v[32];
    float mx = -3.0e38f;
    for (int c = 0; c <= nc; c++) {
        half8 hv = *(half8*)(srow + lane * 8 + c * 512);
#pragma unroll
        for (int i = 0; i < 8; i++) {
            int n = lane * 8 + c * 512 + i;
            float s = (n <= r) ? (float)hv[i] : -3.0e38f;
            v[c * 8 + i] = s; mx = fmaxf(mx, s);
        }
    }
#pragma unroll
    for (int off = 32; off; off >>= 1) mx = fmaxf(mx, __shfl_xor(mx, off));
    float sum = 0.f;
    for (int c = 0; c <= nc; c++)
#pragma unroll
        for (int i = 0; i < 8; i++) {
            int n = lane * 8 + c * 512 + i;
            float e = (n <= r) ? __expf(v[c * 8 + i] - mx) : 0.f;
            v[c * 8 + i] = e; sum += e;
        }
#pragma unroll
    for (int off = 32; off; off >>= 1) sum += __shfl_xor(sum, off);
    float inv = 1.f / sum;
    for (int c = 0; c <= nc; c++) {
        half8 o;
#pragma unroll
        for (int i = 0; i < 8; i++) o[i] = (_Float16)(v[c * 8 + i] * inv);
        *(half8*)(srow + lane * 8 + c * 512) = o;
    }
}

extern "C" void kernel_launch(void* const* d_in, const int* in_sizes, int n_in,
                              void* d_out, int out_size, void* d_ws, size_t ws_size,
                              hipStream_t stream) {
    const int B = 4, S = 2048, D = 512, H = 4, U = 1024;
    const float* x     = (const float*)d_in[0];
    const float* gamma = (const float*)d_in[1];
    const float* beta  = (const float*)d_in[2];
    const float* Wq    = (const float*)d_in[3];
    const float* Wk    = (const float*)d_in[4];
    const float* Wv    = (const float*)d_in[5];
    const float* Wout  = (const float*)d_in[6];
    float* out = (float*)d_out;

    char* ws = (char*)d_ws;
    const size_t MiB = 1ull << 20;
    const long long SD = SDo, UD = UDo, SU = SUo, US = USo;

    // W regions must stay adjacent (projQK offB spans WqT..WkT).
    _Float16* xn  = (_Float16*)(ws + 0);         //  8 MiB [B*S, D]
    _Float16* WqT = (_Float16*)(ws + 8  * MiB);  //  4 MiB [H, U, D]
    _Float16* WkT = (_Float16*)(ws + 12 * MiB);  //  4 MiB (adjacent!)
    _Float16* WvT = (_Float16*)(ws + 16 * MiB);  //  4 MiB
    _Float16* WoT = (_Float16*)(ws + 20 * MiB);  //  4 MiB [D, H*U]

    tr_k<<<dim3(U / 32, D / 32, H), dim3(32, 8), 0, stream>>>(Wq, WqT, D, U);
    tr_k<<<dim3(U / 32, D / 32, H), dim3(32, 8), 0, stream>>>(Wk, WkT, D, U);
    tr_k<<<dim3(U / 32, D / 32, H), dim3(32, 8), 0, stream>>>(Wv, WvT, D, U);
    tr_k<<<dim3(D / 32, (H * U) / 32, 1), dim3(32, 8), 0, stream>>>(Wout, WoT, H * U, D);
    ln_k<<<B * S, 64, 0, stream>>>(x, gamma, beta, xn);

    if (ws_size >= 168 * MiB) {
        // ---- pair-batched fast path, peak 152 MiB ----
        // qk region [qk][h][b2][S,U]: 64 MiB @24; sc [h][b2][S,S]: 64 MiB @88
        // vT [h][b2][U,S] reuses q-space @24 (32 MiB); cat [b2][S,H*U] reuses k @56
        _Float16* qk  = (_Float16*)(ws + 24 * MiB);
        _Float16* kk  = qk + 8 * SU;                  // k sub-region @56
        _Float16* sc  = (_Float16*)(ws + 88 * MiB);
        _Float16* vt  = qk;                           // after scores, q dead
        _Float16* cat = kk;                           // after scores, k dead

        for (int p = 0; p < 2; p++) {
            const _Float16* xnp = xn + (long long)p * 2 * SD;
            float* outp = out + (long long)p * 2 * SD;
            // a. projQK: z = qk*8+b2*4+h (16) ; M=S,N=U,K=D
            gemm_bt<<<dim3(U / 128, S / 128, 16), 256, 0, stream>>>(xnp, WqT, qk, D, U, 0, 1);
            // b. scores: z = h*2+b2 (8) ; M=S,N=S,K=U ; causal skip
            gemm_bt<<<dim3(S / 128, S / 128, 8), 256, 0, stream>>>(qk, kk, sc, U, S, 4, 2);
            // c. softmax over 8*S rows
            softmax_h<<<8 * S / 4, 256, 0, stream>>>(sc, S);
            // d. projV into q-space: z = h*2+b2 ; M=U,N=S,K=D
            gemm_bt<<<dim3(S / 128, U / 128, 8), 256, 0, stream>>>(WvT, xnp, vt, D, S, 0, 3);
            // e. PV into k-space: z = h*2+b2 ; M=S,N=U,K=S, kend=m0+128
            gemm_bt<<<dim3(U / 128, S / 128, 8), 256, 0, stream>>>(sc, vt, cat, S, H * U, 8, 4);
            // f. out pair: M=2S, N=D, K=H*U, fp32
            gemm_bt<<<dim3(D / 128, 2 * S / 128, 1), 256, 0, stream>>>(cat, WoT, outp,
                H * U, D, 1, 0);
        }
    } else {
        // ---- fallback: 96 MiB per-batch (R7 structure) ----
        _Float16* qb   = (_Float16*)(ws + 24 * MiB);  // 16 MiB [2H][S,U] (q then k)
        _Float16* vTb  = (_Float16*)(ws + 56 * MiB);  // 16 MiB [H][U,S]
        _Float16* catb = (_Float16*)(ws + 72 * MiB);  // 16 MiB [S,H*U]
        _Float16* sc   = (_Float16*)(ws + 88 * MiB);  //  8 MiB [S,S]

        for (int b = 0; b < B; b++) {
            const _Float16* xnb = xn + (long long)b * SD;
            gemm_bt<<<dim3(U / 128, S / 128, 2 * H), 256, 0, stream>>>(xnb, WqT, qb, D, U, 0, 6);
            gemm_bt<<<dim3(S / 128, U / 128, H), 256, 0, stream>>>(WvT, xnb, vTb, D, S, 0, 7);
            for (int h = 0; h < H; h++) {
                gemm_bt<<<dim3(S / 128, S / 128, 1), 256, 0, stream>>>(qb + (long long)h * SU,
                    qb + (long long)(H + h) * SU, sc, U, S, 4, 0);
                softmax_h<<<S / 4, 256, 0, stream>>>(sc, S);
                gemm_bt<<<dim3(U / 128, S / 128, 1), 256, 0, stream>>>(sc,
                    vTb + (long long)h * US, (void*)(catb + (long long)h * U), S, H * U, 8, 0);
            }
            gemm_bt<<<dim3(D / 128, S / 128, 1), 256, 0, stream>>>(catb, WoT,
                (void*)(out + (long long)b * SD), H * U, D, 1, 0);
        }
    }
}